// Round 1
// baseline (336.589 us; speedup 1.0000x reference)
//
#include <hip/hip_runtime.h>
#include <math.h>

// CDistLoss on MI355X.
// Key identities (see analysis): negatives contribute exactly 0 through the relu;
// sample_weight == 1 to ~1e-12 (sum of normalized cumsum is S/(S+eps)); so
// out[i] = (1/4095) * sum_r thr_r * (cd_r/S_d + 0.1)/(r/S_a + 0.1)
// with p_r = rank of r-th positive = #{k (incl self): d_ik < thr_r},
// ca_r = r, cd_r = p_r - r, S_a = sum_r (4096 - p_r), S_d = 4095*4096/2 - S_a.

#define N 4096
#define DF 128
#define MAXP 128      // max positives per row (true P ~ 63 +- 8; P>128 prob ~ 0)
#define TSTR 128      // thr row stride (floats)
#define NBUCK 129     // buckets 0..P (P<=128)
#define HSTR 132      // hist row stride (u32), 16B-aligned rows

// ---------------- kernel 1: row squared norms ----------------
__global__ void k_sq(const float* __restrict__ x, float* __restrict__ sq) {
  const int wave = threadIdx.x >> 6, lane = threadIdx.x & 63;
  const int row = (blockIdx.x << 2) + wave;
  const float* xr = x + row * DF;
  float a = xr[lane], b = xr[lane + 64];
  float v = a * a + b * b;
  #pragma unroll
  for (int off = 32; off; off >>= 1) v += __shfl_down(v, off);
  if (lane == 0) sq[row] = v;
}

// ------- kernel 2: per-row positive distances, sorted; zero hist -------
__global__ void k_thr(const float* __restrict__ x, const int* __restrict__ y,
                      const float* __restrict__ sq, float* __restrict__ thr,
                      int* __restrict__ Pn, unsigned int* __restrict__ hist) {
  __shared__ float xi[DF];
  __shared__ int plist[MAXP];
  __shared__ float dlist[MAXP];
  __shared__ int cnt;
  const int i = blockIdx.x;
  const int tid = threadIdx.x;
  if (tid == 0) cnt = 0;
  if (tid < DF) xi[tid] = x[i * DF + tid];
  for (int b = tid; b < HSTR; b += 256) hist[i * HSTR + b] = 0u;
  __syncthreads();
  const int yi = y[i];
  for (int k = tid; k < N; k += 256) {
    if (k != i && y[k] == yi) {
      int p = atomicAdd(&cnt, 1);
      if (p < MAXP) plist[p] = k;
    }
  }
  __syncthreads();
  const int P = cnt < MAXP ? cnt : MAXP;
  const int wave = tid >> 6, lane = tid & 63;
  const float sqi = sq[i];
  for (int idx = wave; idx < P; idx += 4) {   // one wave per positive: coalesced dot
    const int j = plist[idx];
    const float* xj = x + j * DF;
    float v = xi[lane] * xj[lane] + xi[lane + 64] * xj[lane + 64];
    #pragma unroll
    for (int off = 32; off; off >>= 1) v += __shfl_down(v, off);
    if (lane == 0) dlist[idx] = sqrtf(fmaxf(sqi + sq[j] - 2.0f * v, 1e-12f));
  }
  __syncthreads();
  // O(P^2) rank sort (P ~ 63), tie-break by index == stable argsort
  for (int t = tid; t < P; t += 256) {
    const float dt = dlist[t];
    const int jt = plist[t];
    int r = 0;
    for (int s = 0; s < P; ++s) {
      const float ds = dlist[s];
      r += (ds < dt || (ds == dt && plist[s] < jt)) ? 1 : 0;
    }
    thr[i * TSTR + r] = dt;
  }
  if (tid == 0) Pn[i] = P;
}

// ------- kernel 3: Gram tiles + rank-count histogram (the heavy one) -------
#define ROWS 32
#define CT 256
#define KC 16
#define BPAD 260           // 260 % 32 == 4: spreads banks, keeps float4 alignment
#define COLS_PER_WG 1024

__global__ __launch_bounds__(256, 2) void k_count(
    const float* __restrict__ x, const float* __restrict__ sq,
    const float* __restrict__ thr, const int* __restrict__ Pn,
    unsigned int* __restrict__ hist) {
  __shared__ float A[ROWS][DF];            // 16 KB
  __shared__ float B[KC][BPAD];            // 16.6 KB
  __shared__ float thrL[ROWS][TSTR];       // 16 KB
  __shared__ unsigned int histL[ROWS][NBUCK]; // 16.5 KB
  __shared__ float sqr[ROWS];
  __shared__ int PL[ROWS];

  const int slab = blockIdx.x >> 2;        // 128 row-slabs
  const int cq = blockIdx.x & 3;           // 4 col-quarters
  const int row0 = slab * ROWS;
  const int col0 = cq * COLS_PER_WG;
  const int tid = threadIdx.x;
  const int rg = tid >> 6, cg = tid & 63;  // 4 x 64 thread grid, 8x4 micro-tile

  for (int e = tid; e < ROWS * DF; e += 256) {
    const int r = e >> 7, f = e & 127;
    A[r][f] = x[(row0 + r) * DF + f];
  }
  for (int e = tid; e < ROWS * TSTR; e += 256) {
    const int r = e >> 7, b = e & 127;
    thrL[r][b] = thr[(row0 + r) * TSTR + b];
  }
  for (int e = tid; e < ROWS * NBUCK; e += 256) histL[e / NBUCK][e % NBUCK] = 0u;
  if (tid < ROWS) { sqr[tid] = sq[row0 + tid]; PL[tid] = Pn[row0 + tid]; }

  for (int cb = 0; cb < COLS_PER_WG; cb += CT) {
    float acc[8][4];
    #pragma unroll
    for (int a_ = 0; a_ < 8; ++a_)
      #pragma unroll
      for (int b_ = 0; b_ < 4; ++b_) acc[a_][b_] = 0.f;

    for (int kb = 0; kb < DF; kb += KC) {
      __syncthreads();
      #pragma unroll
      for (int m = 0; m < (CT * KC) / 256; ++m) {   // stage B: 256 cols x 16 feats
        const int e = m * 256 + tid;
        const int c = e >> 4, f = e & 15;
        B[f][c] = x[(col0 + cb + c) * DF + kb + f];
      }
      __syncthreads();
      #pragma unroll
      for (int k4 = 0; k4 < KC; k4 += 4) {
        const float4 b0 = *(const float4*)&B[k4 + 0][cg << 2];
        const float4 b1 = *(const float4*)&B[k4 + 1][cg << 2];
        const float4 b2 = *(const float4*)&B[k4 + 2][cg << 2];
        const float4 b3 = *(const float4*)&B[k4 + 3][cg << 2];
        #pragma unroll
        for (int rr = 0; rr < 8; ++rr) {
          const float4 a = *(const float4*)&A[(rg << 3) + rr][kb + k4];  // broadcast
          acc[rr][0] += a.x * b0.x + a.y * b1.x + a.z * b2.x + a.w * b3.x;
          acc[rr][1] += a.x * b0.y + a.y * b1.y + a.z * b2.y + a.w * b3.y;
          acc[rr][2] += a.x * b0.z + a.y * b1.z + a.z * b2.z + a.w * b3.z;
          acc[rr][3] += a.x * b0.w + a.y * b1.w + a.z * b2.w + a.w * b3.w;
        }
      }
    }
    // epilogue: distance -> bucket (= #{thr < d}) -> LDS histogram
    #pragma unroll
    for (int rr = 0; rr < 8; ++rr) {
      const int r = (rg << 3) + rr;
      const float sa = sqr[r];
      const int P = PL[r];
      #pragma unroll
      for (int cc = 0; cc < 4; ++cc) {
        const int col = col0 + cb + (cg << 2) + cc;
        const float d = sqrtf(fmaxf(sa + sq[col] - 2.0f * acc[rr][cc], 1e-12f));
        int lo = 0;
        #pragma unroll
        for (int st = 128; st; st >>= 1)
          if (lo + st <= P && thrL[r][lo + st - 1] < d) lo += st;
        atomicAdd(&histL[r][lo], 1u);
      }
    }
  }
  __syncthreads();
  for (int e = tid; e < ROWS * NBUCK; e += 256)
    atomicAdd(&hist[(row0 + e / NBUCK) * HSTR + (e % NBUCK)], histL[e / NBUCK][e % NBUCK]);
}

// ---------------- kernel 4: finalize per-row score ----------------
__global__ void k_final(const float* __restrict__ thr, const int* __restrict__ Pn,
                        const unsigned int* __restrict__ hist, float* __restrict__ out) {
  __shared__ unsigned int pre[NBUCK];
  const int i = blockIdx.x;
  const int lane = threadIdx.x;  // 64 threads = 1 wave
  const int P = Pn[i];
  if (lane == 0) {
    unsigned int run = 0;
    for (int b = 0; b < NBUCK; ++b) { run += hist[i * HSTR + b]; pre[b] = run; }
  }
  __syncthreads();
  // p_r (1-based rank in self-dropped list) = pre[r0] - 1 for r0 = r-1
  int sa = 0;
  for (int r0 = lane; r0 < P; r0 += 64) sa += (N + 1) - (int)pre[r0];  // 4096 - p
  #pragma unroll
  for (int off = 32; off; off >>= 1) sa += __shfl_down(sa, off);
  sa = __shfl(sa, 0);
  const float Sa = (float)sa + 1e-7f;
  const float Sd = (float)(8386560 - sa) + 1e-7f;   // 4095*4096/2 - S_a
  float sc = 0.f;
  for (int r0 = lane; r0 < P; r0 += 64) {
    const int p = (int)pre[r0] - 1;
    const float fa = (float)(r0 + 1) / Sa;
    const float fd = (float)(p - (r0 + 1)) / Sd;
    sc += thr[i * TSTR + r0] * (fd + 0.1f) / (fa + 0.1f);
  }
  #pragma unroll
  for (int off = 32; off; off >>= 1) sc += __shfl_down(sc, off);
  if (lane == 0) out[i] = sc * (1.0f / 4095.0f);
}

extern "C" void kernel_launch(void* const* d_in, const int* in_sizes, int n_in,
                              void* d_out, int out_size, void* d_ws, size_t ws_size,
                              hipStream_t stream) {
  const float* x = (const float*)d_in[0];
  const int* y = (const int*)d_in[1];
  float* out = (float*)d_out;
  char* ws = (char*)d_ws;
  float* sq = (float*)ws;                               // 16 KB
  int* Pn = (int*)(ws + (size_t)N * 4);                 // 16 KB
  float* thr = (float*)(ws + (size_t)2 * N * 4);        // 2 MB
  unsigned int* hist = (unsigned int*)(ws + (size_t)2 * N * 4 + (size_t)N * TSTR * 4); // 2.16 MB

  k_sq<<<N / 4, 256, 0, stream>>>(x, sq);
  k_thr<<<N, 256, 0, stream>>>(x, y, sq, thr, Pn, hist);
  k_count<<<(N / ROWS) * 4, 256, 0, stream>>>(x, sq, thr, Pn, hist);
  k_final<<<N, 64, 0, stream>>>(thr, Pn, hist, out);
}

// Round 2
// 266.419 us; speedup vs baseline: 1.2634x; 1.2634x over previous
//
#include <hip/hip_runtime.h>
#include <math.h>
#include <float.h>

// CDistLoss on MI355X — round 2: bf16 MFMA Gram + rank-count histogram.
// out[i] = (1/4095) * sum_r thr_r * (cd_r/S_d + 0.1)/(r/S_a + 0.1)
// p_r = #{k incl self: d2_ik <= thr2_r} (via bucket prefix), cd_r = p_r-1-r,
// S_a = sum_r (4097 - pre_r), S_d = 4095*4096/2 - S_a.  sample_weight == 1
// to ~1e-12. bf16 Gram error -> +-3 rank flips/threshold -> ~1e-6 on out.

#define N 4096
#define DF 128
#define NCLS 64
#define MAXP 128
#define TSTR 128          // thr2 row stride (floats), padded with FLT_MAX to 128
#define HSTR 128          // hist row stride (u32)
#define NBUCK 128

typedef __bf16 bf16x8 __attribute__((ext_vector_type(8)));
typedef float f32x4 __attribute__((ext_vector_type(4)));
typedef unsigned int u32x4 __attribute__((ext_vector_type(4)));

static __device__ __forceinline__ unsigned short f2bf(float f) {
  unsigned int u = __float_as_uint(f);
  unsigned int r = (u + 0x7fffu + ((u >> 16) & 1u)) >> 16;  // RNE
  return (unsigned short)r;
}

// ---- kernel 1: fp32 -> bf16 copy + row squared norms + zero class counters ----
__global__ void k_cvt(const float* __restrict__ x, unsigned short* __restrict__ xb,
                      float* __restrict__ sq, unsigned int* __restrict__ cls_cnt) {
  const int wave = threadIdx.x >> 6, lane = threadIdx.x & 63;
  const int row = (blockIdx.x << 2) + wave;
  if (blockIdx.x == 0 && threadIdx.x < NCLS) cls_cnt[threadIdx.x] = 0u;
  const float2 v = *(const float2*)&x[row * DF + (lane << 1)];
  unsigned int b = (unsigned int)f2bf(v.x) | ((unsigned int)f2bf(v.y) << 16);
  *(unsigned int*)&xb[row * DF + (lane << 1)] = b;
  float s = v.x * v.x + v.y * v.y;
  #pragma unroll
  for (int off = 32; off; off >>= 1) s += __shfl_down(s, off);
  if (lane == 0) sq[row] = s;
}

// ---- kernel 2: bucket samples by class (single block) ----
__global__ void k_classes(const int* __restrict__ y, unsigned int* __restrict__ cls_cnt,
                          int* __restrict__ cls_idx) {
  __shared__ unsigned int c_cnt[NCLS];
  const int tid = threadIdx.x;
  if (tid < NCLS) c_cnt[tid] = 0u;
  __syncthreads();
  for (int k = tid; k < N; k += 256) {
    const int c = y[k];
    const unsigned int pos = atomicAdd(&c_cnt[c], 1u);
    if (pos < MAXP) cls_idx[c * MAXP + pos] = k;
  }
  __syncthreads();
  if (tid < NCLS) cls_cnt[tid] = c_cnt[tid];
}

// ---- kernel 3: per-row sorted positive squared distances (fp32); zero hist ----
__global__ void k_thr(const float* __restrict__ x, const int* __restrict__ y,
                      const float* __restrict__ sq, const unsigned int* __restrict__ cls_cnt,
                      const int* __restrict__ cls_idx, float* __restrict__ thr2,
                      int* __restrict__ Pn, unsigned int* __restrict__ hist) {
  __shared__ float xi[DF];
  __shared__ int plist[MAXP];
  __shared__ float d2l[MAXP];
  __shared__ int pcnt;
  const int i = blockIdx.x;
  const int lane = threadIdx.x;  // 64 threads
  if (lane == 0) pcnt = 0;
  xi[lane] = x[i * DF + lane];
  xi[lane + 64] = x[i * DF + 64 + lane];
  hist[i * HSTR + lane] = 0u;
  hist[i * HSTR + 64 + lane] = 0u;
  const int yi = y[i];
  const unsigned int cm = cls_cnt[yi];
  const int M = cm < MAXP ? (int)cm : MAXP;
  __syncthreads();
  for (int m = lane; m < M; m += 64) {
    const int j = cls_idx[yi * MAXP + m];
    if (j != i) plist[atomicAdd(&pcnt, 1)] = j;
  }
  __syncthreads();
  const int P = pcnt;
  const float sqi = sq[i];
  for (int idx = lane; idx < P; idx += 64) {
    const int j = plist[idx];
    const float* xj = x + (size_t)j * DF;
    float dot = 0.f;
    #pragma unroll
    for (int k = 0; k < DF; k += 4) {
      const float4 v = *(const float4*)&xj[k];
      dot += xi[k] * v.x + xi[k + 1] * v.y + xi[k + 2] * v.z + xi[k + 3] * v.w;
    }
    d2l[idx] = fmaxf(sqi + sq[j] - 2.0f * dot, 1e-12f);
  }
  __syncthreads();
  // rank sort (P ~ 63), tie-break by index -> deterministic
  for (int t = lane; t < P; t += 64) {
    const float dt = d2l[t];
    const int jt = plist[t];
    int r = 0;
    for (int s = 0; s < P; ++s) {
      const float ds = d2l[s];
      r += (ds < dt || (ds == dt && plist[s] < jt)) ? 1 : 0;
    }
    thr2[i * TSTR + r] = dt;
  }
  for (int r = lane; r < TSTR; r += 64)
    if (r >= P) thr2[i * TSTR + r] = FLT_MAX;   // pad -> branchless search
  if (lane == 0) Pn[i] = P;
}

// ---- kernel 4: MFMA Gram tiles + rank-count histogram (the heavy one) ----
#define ROWS 16
#define CS 8            // column splits -> grid = 256*CS blocks
#define TPAD 132
#define HPAD 132

__global__ __launch_bounds__(256, 6) void k_count(
    const unsigned short* __restrict__ xb, const float* __restrict__ sq,
    const float* __restrict__ thr2, unsigned int* __restrict__ hist) {
  __shared__ float t2[ROWS][TPAD];            // 8.25 KB
  __shared__ unsigned int histL[ROWS][HPAD];  // 8.25 KB

  const int rb = blockIdx.x >> 3;        // 256 row-blocks of 16
  const int cs = blockIdx.x & 7;         // 8 col-splits of 512
  const int row0 = rb * ROWS;
  const int col0 = cs * 512;
  const int tid = threadIdx.x;
  const int wave = tid >> 6, lane = tid & 63;
  const int l15 = lane & 15, lg = lane >> 4;

  for (int e = tid; e < ROWS * TSTR; e += 256)
    t2[e >> 7][e & 127] = thr2[(size_t)(row0 + (e >> 7)) * TSTR + (e & 127)];
  for (int e = tid; e < ROWS * HPAD; e += 256) ((unsigned int*)histL)[e] = 0u;

  // A fragments: 16 rows held in registers for the whole kernel (m97 pattern:
  // Gram = X * X^T == A*B^T with both fragments loaded identically).
  const u32x4* ap = (const u32x4*)(xb + (size_t)(row0 + l15) * DF + (lg << 3));
  const bf16x8 a0 = __builtin_bit_cast(bf16x8, ap[0]);
  const bf16x8 a1 = __builtin_bit_cast(bf16x8, ap[4]);
  const bf16x8 a2 = __builtin_bit_cast(bf16x8, ap[8]);
  const bf16x8 a3 = __builtin_bit_cast(bf16x8, ap[12]);
  // sq of this lane's 4 output rows (C layout: row = lg*4 + reg)
  float sqa[4];
  #pragma unroll
  for (int r = 0; r < 4; ++r) sqa[r] = sq[row0 + lg * 4 + r];
  __syncthreads();

  const int jbase = col0 + wave * 128;   // each wave: 128 cols = 8 tiles
  for (int t = 0; t < 8; ++t) {
    const int j0 = jbase + t * 16;
    const u32x4* bp = (const u32x4*)(xb + (size_t)(j0 + l15) * DF + (lg << 3));
    const bf16x8 b0 = __builtin_bit_cast(bf16x8, bp[0]);
    const bf16x8 b1 = __builtin_bit_cast(bf16x8, bp[4]);
    const bf16x8 b2 = __builtin_bit_cast(bf16x8, bp[8]);
    const bf16x8 b3 = __builtin_bit_cast(bf16x8, bp[12]);
    f32x4 acc = {0.f, 0.f, 0.f, 0.f};
    acc = __builtin_amdgcn_mfma_f32_16x16x32_bf16(a0, b0, acc, 0, 0, 0);
    acc = __builtin_amdgcn_mfma_f32_16x16x32_bf16(a1, b1, acc, 0, 0, 0);
    acc = __builtin_amdgcn_mfma_f32_16x16x32_bf16(a2, b2, acc, 0, 0, 0);
    acc = __builtin_amdgcn_mfma_f32_16x16x32_bf16(a3, b3, acc, 0, 0, 0);
    const float sqc = sq[j0 + l15];      // C layout: col = lane & 15
    #pragma unroll
    for (int r = 0; r < 4; ++r) {
      const int lr = lg * 4 + r;
      const float d2 = fmaxf(fmaf(-2.0f, acc[r], sqa[r] + sqc), 1e-12f);
      int lo = 0;                        // branchless rank over 128 padded thr2
      #pragma unroll
      for (int st = 64; st; st >>= 1) lo += (t2[lr][lo + st - 1] < d2) ? st : 0;
      atomicAdd(&histL[lr][lo], 1u);
    }
  }
  __syncthreads();
  for (int e = tid; e < ROWS * NBUCK; e += 256) {
    const unsigned int v = histL[e >> 7][e & 127];
    if (v) atomicAdd(&hist[(size_t)(row0 + (e >> 7)) * HSTR + (e & 127)], v);
  }
}

// ---- kernel 5: finalize per-row score ----
__global__ void k_final(const float* __restrict__ thr2, const int* __restrict__ Pn,
                        const unsigned int* __restrict__ hist, float* __restrict__ out) {
  __shared__ unsigned int pre[NBUCK];
  const int i = blockIdx.x;
  const int lane = threadIdx.x;  // 64 threads
  pre[lane] = hist[i * HSTR + lane];
  pre[lane + 64] = hist[i * HSTR + 64 + lane];
  __syncthreads();
  if (lane == 0) {
    unsigned int run = 0;
    for (int b = 0; b < NBUCK; ++b) { run += pre[b]; pre[b] = run; }
  }
  __syncthreads();
  const int P = Pn[i];
  int sa = 0;
  for (int r0 = lane; r0 < P; r0 += 64) sa += (N + 1) - (int)pre[r0];
  #pragma unroll
  for (int off = 32; off; off >>= 1) sa += __shfl_down(sa, off);
  sa = __shfl(sa, 0);
  const float Sa = (float)sa + 1e-7f;
  const float Sd = (float)(8386560 - sa) + 1e-7f;   // 4095*4096/2 - S_a
  float sc = 0.f;
  for (int r0 = lane; r0 < P; r0 += 64) {
    const int p = (int)pre[r0] - 1;
    const float fa = (float)(r0 + 1) / Sa;
    const float fd = (float)(p - (r0 + 1)) / Sd;
    sc += sqrtf(thr2[i * TSTR + r0]) * (fd + 0.1f) / (fa + 0.1f);
  }
  #pragma unroll
  for (int off = 32; off; off >>= 1) sc += __shfl_down(sc, off);
  if (lane == 0) out[i] = sc * (1.0f / 4095.0f);
}

extern "C" void kernel_launch(void* const* d_in, const int* in_sizes, int n_in,
                              void* d_out, int out_size, void* d_ws, size_t ws_size,
                              hipStream_t stream) {
  const float* x = (const float*)d_in[0];
  const int* y = (const int*)d_in[1];
  float* out = (float*)d_out;
  char* ws = (char*)d_ws;
  unsigned short* xb = (unsigned short*)ws;                       // 1 MB
  float* sq       = (float*)(ws + 1048576);                      // 16 KB
  int* Pn         = (int*)(ws + 1048576 + 16384);                // 16 KB
  unsigned int* cls_cnt = (unsigned int*)(ws + 1048576 + 32768); // 256 B
  int* cls_idx    = (int*)(ws + 1048576 + 32768 + 256);          // 32 KB
  float* thr2     = (float*)(ws + 1048576 + 65792);              // 2 MB
  unsigned int* hist = (unsigned int*)(ws + 1048576 + 65792 + 2097152); // 2 MB

  k_cvt<<<N / 4, 256, 0, stream>>>(x, xb, sq, cls_cnt);
  k_classes<<<1, 256, 0, stream>>>(y, cls_cnt, cls_idx);
  k_thr<<<N, 64, 0, stream>>>(x, y, sq, cls_cnt, cls_idx, thr2, Pn, hist);
  k_count<<<256 * CS, 256, 0, stream>>>(xb, sq, thr2, hist);
  k_final<<<N, 64, 0, stream>>>(thr2, Pn, hist, out);
}